// Round 3
// baseline (2299.851 us; speedup 1.0000x reference)
//
#include <hip/hip_runtime.h>
#include <hip/hip_bf16.h>

// ---------------------------------------------------------------------------
// DeepSeek MoE forward on MI355X (gfx950). R3 restructure:
//  - fp32->bf16 weight conversion fused into GEMM B-staging (no conv kernels,
//    weights read once as fp32)
//  - shared expert fused as expert #8 into single GEMM1 + single GEMM2
//  - out zero-initialized; GEMM2 all-atomic epilogue
//  - XCD swizzle pins each B-panel (big tensor) to one XCD, y innermost
// ---------------------------------------------------------------------------

typedef unsigned short u16;
typedef unsigned int u32;

typedef short bf16x8 __attribute__((ext_vector_type(8)));
typedef float f32x4 __attribute__((ext_vector_type(4)));

#define GLD16(g, l)                                                            \
  __builtin_amdgcn_global_load_lds(                                            \
      (const __attribute__((address_space(1))) void*)(g),                      \
      (__attribute__((address_space(3))) void*)(l), 16, 0, 0)

__device__ __forceinline__ u32 rne16(float f) {
  u32 u = __float_as_uint(f);
  return (u + 0x7fffu + ((u >> 16) & 1u)) >> 16;
}
__device__ __forceinline__ u16 bf16of(float f) { return (u16)rne16(f); }
__device__ __forceinline__ u32 pk2(float lo, float hi) {
  __hip_bfloat162 h = __float22bfloat162_rn(float2{lo, hi});
  return *(u32*)&h;
}

// ---------------- meta layout (int* meta at ws+0) ----------------
// [0..7] cnt[e]   [8..15] padded[e]   [16..25] base[e] (seg 8 = shared,
// base[8]=routed total, base[9]=total rows)   float at meta+32: z-loss acc

__global__ void zero_meta_kernel(int* __restrict__ meta) {
  int t = threadIdx.x;
  if (t < 8) meta[t] = 0;
  if (t == 8) ((float*)(meta + 32))[0] = 0.0f;
}

__global__ void zero_out_kernel(float* __restrict__ out) {
  int i = blockIdx.x * 256 + threadIdx.x;
  ((float4*)out)[i] = make_float4(0.f, 0.f, 0.f, 0.f);
}

// one wave (64 threads) per token
__global__ void router_kernel(const float* __restrict__ x,
                              const float* __restrict__ rw,
                              u16* __restrict__ xb, int* __restrict__ tlist,
                              float* __restrict__ gwv, int* __restrict__ meta) {
  int tok = blockIdx.x;
  int lane = threadIdx.x;
  const float* xr = x + (size_t)tok * 1024;
  float acc[8] = {0.f, 0.f, 0.f, 0.f, 0.f, 0.f, 0.f, 0.f};
#pragma unroll
  for (int c = 0; c < 16; c++) {
    float xv = xr[lane + 64 * c];
    xb[(size_t)tok * 1024 + lane + 64 * c] = bf16of(xv);
#pragma unroll
    for (int e = 0; e < 8; e++) acc[e] += xv * rw[e * 1024 + lane + 64 * c];
  }
#pragma unroll
  for (int e = 0; e < 8; e++) {
    float v = acc[e];
    for (int m = 32; m > 0; m >>= 1) v += __shfl_xor(v, m, 64);
    acc[e] = v;
  }
  if (lane == 0) {
    float z = 0.f;
#pragma unroll
    for (int e = 0; e < 8; e++) z += acc[e] * acc[e];
    atomicAdd((float*)(meta + 32), z);
    int i1 = 0;
    float b1 = acc[0];
#pragma unroll
    for (int e = 1; e < 8; e++)
      if (acc[e] > b1) { b1 = acc[e]; i1 = e; }
    int i2 = -1;
    float b2 = -3.0e38f;
#pragma unroll
    for (int e = 0; e < 8; e++)
      if (e != i1 && acc[e] > b2) { b2 = acc[e]; i2 = e; }
    float w1 = 1.0f / (1.0f + __expf(b2 - b1));  // = p1/(p1+p2)
    float w2 = 1.0f - w1;
    int s1 = atomicAdd(&meta[i1], 1);
    tlist[i1 * 4096 + s1] = tok;
    gwv[i1 * 4096 + s1] = w1;
    int s2 = atomicAdd(&meta[i2], 1);
    tlist[i2 * 4096 + s2] = tok;
    gwv[i2 * 4096 + s2] = w2;
  }
}

__global__ void finalize_kernel(int* __restrict__ meta, float* __restrict__ out) {
  if (threadIdx.x == 0) {
    int* basep = meta + 16;
    int base = 0;
    float lb = 0.f;
    const float invsum = 1.0f / 12288.0f;  // sum loads = 8192 + 4096
    const float ideal = 1.0f / 9.0f;
    for (int e = 0; e < 8; e++) {
      int c = meta[e];
      int p = (c + 127) & ~127;
      meta[8 + e] = p;
      basep[e] = base;
      base += p;
      float d = (float)c * invsum - ideal;
      lb += d * d;
    }
    basep[8] = base;          // shared segment start
    basep[9] = base + 4096;   // total rows
    float dsh = 4096.0f * invsum - ideal;
    lb += dsh * dsh;
    lb *= (1.0f / 9.0f);
    float z = ((float*)(meta + 32))[0] * (1.0f / 4096.0f);
    out[4194304] = 0.01f * lb + 0.01f * z;  // total_aux_loss
  }
}

// one block (128 thr) per gathered row; zero pads; shared seg = identity
__global__ void gather_kernel(const u16* __restrict__ xb, u16* __restrict__ Ag,
                              const int* __restrict__ tlist,
                              const int* __restrict__ meta) {
  int r = blockIdx.x;
  int t = threadIdx.x;
  const int* base = meta + 16;
  uint4 val = make_uint4(0u, 0u, 0u, 0u);
  if (r >= base[8]) {
    if (r < base[9]) {
      int tok = r - base[8];
      val = *((const uint4*)(xb + (size_t)tok * 1024) + t);
    }
  } else {
    int e = 0;
#pragma unroll
    for (int q = 1; q < 8; q++)
      if (r >= base[q]) e = q;
    int s = r - base[e];
    if (s < meta[e]) {
      int tok = tlist[e * 4096 + s];
      val = *((const uint4*)(xb + (size_t)tok * 1024) + t);
    }
  }
  *((uint4*)(Ag + (size_t)r * 1024) + t) = val;
}

// ---------------- GEMM1: h = silu(A@Wg^T) * (A@Wu^T), bf16 out -------------
// A [rows,1024] bf16 (GLD16), Wg/Wu fp32 [N,K] converted in staging.
// grid 3328: xcd=bid&7 (n_lo), slot=bid>>3 in [0,416): n_hi=slot/104,
// y=slot%104 (y innermost on each XCD -> B panel pinned to one XCD L2)
__global__ __launch_bounds__(256, 4) void gemm1_kernel(
    const u16* __restrict__ A, const float* __restrict__ gw,
    const float* __restrict__ uw, const float* __restrict__ sg,
    const float* __restrict__ su, u16* __restrict__ Hout,
    const int* __restrict__ meta) {
  __shared__ u16 sA[128 * 32];
  __shared__ u16 sBg[128 * 32];
  __shared__ u16 sBu[128 * 32];

  int bid = blockIdx.x;
  int xcd = bid & 7;
  int slot = bid >> 3;
  int n_hi = slot / 104;
  int y = slot - n_hi * 104;
  int n0 = (n_hi * 8 + xcd) << 7;

  const int* base = meta + 16;
  int r0 = y << 7;
  if (r0 >= base[9]) return;
  int e = 0;
#pragma unroll
  for (int q = 1; q < 9; q++)
    if (r0 >= base[q]) e = q;
  const float *gptr, *uptr;
  if (e == 8) {
    gptr = sg;
    uptr = su;
  } else {
    gptr = gw + (size_t)e * 4194304;
    uptr = uw + (size_t)e * 4194304;
  }

  int t = threadIdx.x;
  const u16* aP = A + (size_t)(r0 + (t >> 2)) * 1024 + (t & 3) * 8;
  u16* aD = sA + t * 8;
  int brow = t >> 1, bcol = (t & 1) << 4;
  const float* gP = gptr + (size_t)(n0 + brow) * 1024 + bcol;
  const float* uP = uptr + (size_t)(n0 + brow) * 1024 + bcol;
  uint4* gD = (uint4*)(sBg + brow * 32 + bcol);
  uint4* uD = (uint4*)(sBu + brow * 32 + bcol);

  int lane = t & 63, wid = t >> 6;
  int wm = wid >> 1, wn = wid & 1;
  int l15 = lane & 15, quad = lane >> 4;
  const u16* aR = sA + (wm * 64 + l15) * 32 + quad * 8;
  const u16* gR = sBg + (wn * 64 + l15) * 32 + quad * 8;
  const u16* uR = sBu + (wn * 64 + l15) * 32 + quad * 8;

  f32x4 accg[4][4] = {};
  f32x4 accu[4][4] = {};

#pragma unroll 1
  for (int kk = 0; kk < 32; kk++) {
    if (kk) __syncthreads();
    GLD16(aP, aD);
    GLD16(aP + 64 * 1024, aD + 2048);
    aP += 32;
    float4 g0 = ((const float4*)gP)[0], g1 = ((const float4*)gP)[1];
    float4 g2 = ((const float4*)gP)[2], g3 = ((const float4*)gP)[3];
    float4 v0 = ((const float4*)uP)[0], v1 = ((const float4*)uP)[1];
    float4 v2 = ((const float4*)uP)[2], v3 = ((const float4*)uP)[3];
    gP += 32;
    uP += 32;
    uint4 pa, pb;
    pa.x = pk2(g0.x, g0.y); pa.y = pk2(g0.z, g0.w);
    pa.z = pk2(g1.x, g1.y); pa.w = pk2(g1.z, g1.w);
    pb.x = pk2(g2.x, g2.y); pb.y = pk2(g2.z, g2.w);
    pb.z = pk2(g3.x, g3.y); pb.w = pk2(g3.z, g3.w);
    gD[0] = pa;
    gD[1] = pb;
    pa.x = pk2(v0.x, v0.y); pa.y = pk2(v0.z, v0.w);
    pa.z = pk2(v1.x, v1.y); pa.w = pk2(v1.z, v1.w);
    pb.x = pk2(v2.x, v2.y); pb.y = pk2(v2.z, v2.w);
    pb.z = pk2(v3.x, v3.y); pb.w = pk2(v3.z, v3.w);
    uD[0] = pa;
    uD[1] = pb;
    __syncthreads();

    bf16x8 af[4];
#pragma unroll
    for (int i = 0; i < 4; i++) af[i] = *(const bf16x8*)(aR + i * 512);
#pragma unroll
    for (int j = 0; j < 4; j++) {
      bf16x8 bg = *(const bf16x8*)(gR + j * 512);
      bf16x8 bu = *(const bf16x8*)(uR + j * 512);
#pragma unroll
      for (int i = 0; i < 4; i++) {
        accg[i][j] =
            __builtin_amdgcn_mfma_f32_16x16x32_bf16(af[i], bg, accg[i][j], 0, 0, 0);
        accu[i][j] =
            __builtin_amdgcn_mfma_f32_16x16x32_bf16(af[i], bu, accu[i][j], 0, 0, 0);
      }
    }
  }

  // epilogue: h = silu(g)*u ; C/D map: row=(lane>>4)*4+reg, col=lane&15
#pragma unroll
  for (int i = 0; i < 4; i++) {
    int row = r0 + wm * 64 + i * 16 + quad * 4;
#pragma unroll
    for (int r = 0; r < 4; r++) {
      u16* hrow = Hout + (size_t)(row + r) * 4096 + n0 + wn * 64 + l15;
#pragma unroll
      for (int j = 0; j < 4; j++) {
        float g = accg[i][j][r];
        float u = accu[i][j][r];
        float s = g / (1.0f + __expf(-g));
        hrow[j * 16] = bf16of(s * u);
      }
    }
  }
}

// ---------------- GEMM2: out[token] += w * (A@Wd^T), all-atomic ------------
// A [rows,4096] bf16 (GLD16), Wd fp32 [N=1024,K=4096] converted in staging.
// grid 1664: xcd=bid&7 (=n-tile), slot=bid>>3 in [0,208): z=slot/104,
// y=slot%104; k0=z*2048 (64 ksteps)
__global__ __launch_bounds__(256, 5) void gemm2_kernel(
    const u16* __restrict__ A, const float* __restrict__ dw,
    const float* __restrict__ sd, float* __restrict__ out,
    const int* __restrict__ meta, const int* __restrict__ tlist,
    const float* __restrict__ gwv) {
  __shared__ u16 sA[128 * 32];
  __shared__ u16 sB[128 * 32];

  int bid = blockIdx.x;
  int xcd = bid & 7;
  int slot = bid >> 3;
  int z = slot / 104;
  int y = slot - z * 104;
  int n0 = xcd << 7;
  int k0 = z << 11;

  const int* base = meta + 16;
  int r0 = y << 7;
  if (r0 >= base[9]) return;
  int e = 0;
#pragma unroll
  for (int q = 1; q < 9; q++)
    if (r0 >= base[q]) e = q;
  const float* dptr = (e == 8) ? sd : dw + (size_t)e * 4194304;

  int t = threadIdx.x;
  const u16* aP = A + (size_t)(r0 + (t >> 2)) * 4096 + k0 + (t & 3) * 8;
  u16* aD = sA + t * 8;
  int brow = t >> 1, bcol = (t & 1) << 4;
  const float* bP = dptr + (size_t)(n0 + brow) * 4096 + k0 + bcol;
  uint4* bD = (uint4*)(sB + brow * 32 + bcol);

  int lane = t & 63, wid = t >> 6;
  int wm = wid >> 1, wn = wid & 1;
  int l15 = lane & 15, quad = lane >> 4;
  const u16* aR = sA + (wm * 64 + l15) * 32 + quad * 8;
  const u16* bR = sB + (wn * 64 + l15) * 32 + quad * 8;

  f32x4 acc[4][4] = {};

#pragma unroll 1
  for (int kk = 0; kk < 64; kk++) {
    if (kk) __syncthreads();
    GLD16(aP, aD);
    GLD16(aP + 64 * 4096, aD + 2048);
    aP += 32;
    float4 b0 = ((const float4*)bP)[0], b1 = ((const float4*)bP)[1];
    float4 b2 = ((const float4*)bP)[2], b3 = ((const float4*)bP)[3];
    bP += 32;
    uint4 pa, pb2;
    pa.x = pk2(b0.x, b0.y); pa.y = pk2(b0.z, b0.w);
    pa.z = pk2(b1.x, b1.y); pa.w = pk2(b1.z, b1.w);
    pb2.x = pk2(b2.x, b2.y); pb2.y = pk2(b2.z, b2.w);
    pb2.z = pk2(b3.x, b3.y); pb2.w = pk2(b3.z, b3.w);
    bD[0] = pa;
    bD[1] = pb2;
    __syncthreads();

    bf16x8 af[4];
#pragma unroll
    for (int i = 0; i < 4; i++) af[i] = *(const bf16x8*)(aR + i * 512);
#pragma unroll
    for (int j = 0; j < 4; j++) {
      bf16x8 bb = *(const bf16x8*)(bR + j * 512);
#pragma unroll
      for (int i = 0; i < 4; i++)
        acc[i][j] =
            __builtin_amdgcn_mfma_f32_16x16x32_bf16(af[i], bb, acc[i][j], 0, 0, 0);
    }
  }

  if (e == 8) {
    // shared expert rows: tok = r - base[8], weight 1.0
#pragma unroll
    for (int i = 0; i < 4; i++) {
#pragma unroll
      for (int r = 0; r < 4; r++) {
        int tok = r0 - base[8] + wm * 64 + i * 16 + quad * 4 + r;
        float* orow = out + (size_t)tok * 1024 + n0 + wn * 64 + l15;
#pragma unroll
        for (int j = 0; j < 4; j++) unsafeAtomicAdd(orow + j * 16, acc[i][j][r]);
      }
    }
  } else {
    int cnt_e = meta[e];
    int base_e = base[e];
#pragma unroll
    for (int i = 0; i < 4; i++) {
#pragma unroll
      for (int r = 0; r < 4; r++) {
        int s = r0 - base_e + wm * 64 + i * 16 + quad * 4 + r;
        if (s < cnt_e) {
          int tok = tlist[e * 4096 + s];
          float w = gwv[e * 4096 + s];
          float* orow = out + (size_t)tok * 1024 + n0 + wn * 64 + l15;
#pragma unroll
          for (int j = 0; j < 4; j++)
            unsafeAtomicAdd(orow + j * 16, w * acc[i][j][r]);
        }
      }
    }
  }
}

// ---------------------------------------------------------------------------
extern "C" void kernel_launch(void* const* d_in, const int* in_sizes, int n_in,
                              void* d_out, int out_size, void* d_ws,
                              size_t ws_size, hipStream_t stream) {
  const float* x = (const float*)d_in[0];
  const float* rw = (const float*)d_in[1];
  const float* gw_ = (const float*)d_in[2];
  const float* uw_ = (const float*)d_in[3];
  const float* dw_ = (const float*)d_in[4];
  const float* sg = (const float*)d_in[5];
  const float* su = (const float*)d_in[6];
  const float* sd = (const float*)d_in[7];
  float* out = (float*)d_out;
  char* ws = (char*)d_ws;

  int* meta = (int*)(ws + 0);           // 256 B
  int* tlist = (int*)(ws + 256);        // 128 KB
  float* gwv = (float*)(ws + 131328);   // 128 KB
  u16* xb = (u16*)(ws + 262400);        // 8 MB
  u16* Ag = (u16*)(ws + 8651008);       // 26 MB (13312 x 1024 bf16)
  u16* Hb = (u16*)(ws + 35913984);      // 104 MB (13312 x 4096 bf16)

  zero_meta_kernel<<<1, 64, 0, stream>>>(meta);
  zero_out_kernel<<<4096, 256, 0, stream>>>(out);
  router_kernel<<<4096, 64, 0, stream>>>(x, rw, xb, tlist, gwv, meta);
  finalize_kernel<<<1, 64, 0, stream>>>(meta, out);
  gather_kernel<<<13312, 128, 0, stream>>>(xb, Ag, tlist, meta);

  // one fused GEMM1 (8 routed + shared), one fused GEMM2 (all-atomic)
  gemm1_kernel<<<3328, 256, 0, stream>>>(Ag, gw_, uw_, sg, su, Hb, meta);
  gemm2_kernel<<<1664, 256, 0, stream>>>(Hb, dw_, sd, out, meta, tlist, gwv);
}